// Round 10
// baseline (2566.801 us; speedup 1.0000x reference)
//
#include <hip/hip_runtime.h>
#include <hip/hip_bf16.h>

#define DEVINL __device__ __forceinline__

typedef __attribute__((ext_vector_type(8))) __bf16 bf16x8;
typedef __attribute__((ext_vector_type(4))) float f32x4;
typedef __attribute__((ext_vector_type(4))) unsigned short us4;

DEVINL unsigned short f2bf(float f) {
  union { float f; unsigned int u; } c;
  c.f = f;
  unsigned int u = c.u;
  u += 0x7fffu + ((u >> 16) & 1u);   // RNE
  return (unsigned short)(u >> 16);
}

// jax.nn.gelu(approximate=True) = x * sigmoid(2*sqrt(2/pi)*(x + 0.044715 x^3))
DEVINL float gelu_tanh(float x) {
  float t = 1.5957691216057308f * x * __builtin_fmaf(0.044715f, x * x, 1.0f);
  return x / (1.0f + __expf(-t));
}

DEVINL void ld16(const void* g, void* l) {
  __builtin_amdgcn_global_load_lds(
      (const __attribute__((address_space(1))) void*)g,
      (__attribute__((address_space(3))) void*)l, 16, 0, 0);
}

// ---------------- transpose + fp32->bf16 cast: in[R][C] f32 -> out[C][R] bf16
__global__ __launch_bounds__(256) void transpose_cast_kernel(
    const float* __restrict__ in, unsigned short* __restrict__ out, int R, int C) {
  __shared__ float tile[32][33];
  const int t = threadIdx.x;
  const int r0 = blockIdx.x << 5, c0 = blockIdx.y << 5;
  const int tr = t >> 3, tc = (t & 7) << 2;
  const float4 v = *(const float4*)(in + (size_t)(r0 + tr) * C + c0 + tc);
  tile[tr][tc] = v.x; tile[tr][tc + 1] = v.y;
  tile[tr][tc + 2] = v.z; tile[tr][tc + 3] = v.w;
  __syncthreads();
  us4 o;
  o[0] = f2bf(tile[tc + 0][tr]);
  o[1] = f2bf(tile[tc + 1][tr]);
  o[2] = f2bf(tile[tc + 2][tr]);
  o[3] = f2bf(tile[tc + 3][tr]);
  *(us4*)(out + (size_t)(c0 + tr) * R + r0 + tc) = o;
}

// ---------------- LayerNorm: x[8192][2048] f32 -> ln bf16
__global__ __launch_bounds__(256) void ln_kernel(
    const float* __restrict__ x, const float* __restrict__ gamma,
    const float* __restrict__ beta, unsigned short* __restrict__ out) {
  constexpr int H = 2048;
  const int t = threadIdx.x;
  const size_t row = blockIdx.x;
  const float4* xr = (const float4*)(x + row * H);
  const float4 a = xr[t], b = xr[t + 256];
  float s  = a.x + a.y + a.z + a.w + b.x + b.y + b.z + b.w;
  float s2 = a.x*a.x + a.y*a.y + a.z*a.z + a.w*a.w
           + b.x*b.x + b.y*b.y + b.z*b.z + b.w*b.w;
#pragma unroll
  for (int o = 32; o > 0; o >>= 1) { s += __shfl_xor(s, o); s2 += __shfl_xor(s2, o); }
  __shared__ float red[8];
  const int wid = t >> 6, lane = t & 63;
  if (lane == 0) { red[wid] = s; red[4 + wid] = s2; }
  __syncthreads();
  s  = red[0] + red[1] + red[2] + red[3];
  s2 = red[4] + red[5] + red[6] + red[7];
  const float mean = s * (1.0f / H);
  const float rstd = rsqrtf(s2 * (1.0f / H) - mean * mean + 1e-6f);
  const float4 g0 = ((const float4*)gamma)[t], g1 = ((const float4*)gamma)[t + 256];
  const float4 c0 = ((const float4*)beta)[t],  c1 = ((const float4*)beta)[t + 256];
  us4 o0, o1;
  o0[0] = f2bf((a.x - mean) * rstd * g0.x + c0.x);
  o0[1] = f2bf((a.y - mean) * rstd * g0.y + c0.y);
  o0[2] = f2bf((a.z - mean) * rstd * g0.z + c0.z);
  o0[3] = f2bf((a.w - mean) * rstd * g0.w + c0.w);
  o1[0] = f2bf((b.x - mean) * rstd * g1.x + c1.x);
  o1[1] = f2bf((b.y - mean) * rstd * g1.y + c1.y);
  o1[2] = f2bf((b.z - mean) * rstd * g1.z + c1.z);
  o1[3] = f2bf((b.w - mean) * rstd * g1.w + c1.w);
  *(us4*)(out + row * H + (size_t)t * 4) = o0;
  *(us4*)(out + row * H + 1024 + (size_t)t * 4) = o1;
}

// ---------------- 256-wide tile-pipelined MFMA GEMM, ping-pong fragment regs
// A [*][KDIM] bf16 K-contig. Bm0/Bm1: B^T row panels (K-contig).
// GATED: block tile = 256 rows x 128 cols, two B mats (gelu(y0)*y1 -> bf16 Z[*,8192])
// else : block tile = 256 x 256, Bm1 = Bm0 + 128 rows (f32 Out[*,2048])
// LDS slots per buffer: A-lo | A-hi | B0 | B1 (16K each); double buffered = 128KB.
// TWO fragment register sets (X/Y, ping-pong per tile, loop 2x-unrolled): in S2
// the tail reads of tile t+1 go into the ALTERNATE set and are issued BEFORE
// the deferred MFMA clusters (no WAR) -> the 16 reads drain on the LDS pipe
// under ~1242 cyc of matrix-pipe busy; next tile's LGKM(4) is ~free.
// K-tile t (buffer c, set CUR, next set NXT):
//  S1: LGKM(4) [afCUR_lo+b0CUR ready]; stage A-hi(t+1),B1(t+1); C(0,0);
//      LGKM(0); C(0,1); read afCUR<-A-hi(t) [WAR-ordered]; BAR_B; LGKM(0).
//  S2: stage A-lo(t+2),B0(t+2); vmcnt(4); BAR_A [t+1 visible to ALL waves];
//      read afNXT,b0NXT,b1NXT <- tile t+1; C(1,1); C(1,0)  [read X, write Y].
// Reads/K-tile = 24 b128; 2 barriers/tile. Hazard ledger identical to r9
// (every restage >=1 barrier after its last reader's drain; vmcnt(4) = 12 in
// flight, retire 8 oldest = tile t+1 complete; reads strictly after BAR_A).
template<int KDIM, bool GATED>
__global__ __launch_bounds__(512, 2) void gemm8p(
    const unsigned short* __restrict__ Amat,
    const unsigned short* __restrict__ Bm0,
    const unsigned short* __restrict__ Bm1,
    void* __restrict__ outp, int mCount) {
  constexpr int NT = KDIM / 64;
  __shared__ char lds[131072];
  const int t = threadIdx.x, lane = t & 63, wid = t >> 6;
  const int wr = wid >> 2, wc = wid & 3;                // 2 x 4 waves
  const int bid = (int)blockIdx.x;
  int mb, nb;
  if (GATED && mCount >= 8) {
    // L2-lockstep 2D chunk map: per XCD, 32 concurrent blocks = 8 mb x 4 nb.
    const int xcd = bid & 7, l = bid >> 3;
    const int g = l >> 5, l32 = l & 31;
    const int mchunks = mCount >> 3;
    const int quad = g / mchunks, mch = g % mchunks;
    mb = (mch << 3) | (l32 & 7);
    nb = (xcd << 3) | (quad << 2) | (l32 >> 3);
  } else {
    // gemm2: one nb per XCD (B panel 4MB L2-resident)
    const int nwg = (int)gridDim.x, q = nwg >> 3;
    const int wg = (bid & 7) * q + (bid >> 3);
    mb = wg % mCount; nb = wg / mCount;
  }
  const size_t m0 = (size_t)mb << 8;
  const size_t nrow = (size_t)nb * (GATED ? 128 : 256);
  const unsigned short* aSrc  = Amat + m0 * KDIM;
  const unsigned short* b0Src = Bm0 + nrow * KDIM;
  const unsigned short* b1Src = Bm1 + nrow * KDIM;

  // staging geometry: unit = 128 rows x 64 k x 2B = 16KB = 2 x ld16/thread
  const int srow = (wid << 3) + (lane >> 3);            // 0..63
  const int sOff = srow * KDIM + (((lane & 7) ^ (srow & 7)) << 3);  // pre-swizzled source

  // fragment read geometry
  const int fr = lane & 15, l16 = lane >> 4;
  const int c0 = (l16 ^ (fr & 7)) << 4;                 // ks=0 chunk byte-off (swizzled)
  const int c1 = ((4 | l16) ^ (fr & 7)) << 4;           // ks=1
  const int aRowOff = ((wr << 6) + fr) << 7;
  const int bRowOff = ((wc << 5) + fr) << 7;

  f32x4 acc[2][2][4][2] = {};                           // [mh][g][m][n]

  auto stageU = [&](const unsigned short* src, int ldsOff, int k0) {
    const unsigned short* s = src + sOff + k0;
    ld16(s, lds + ldsOff + (wid << 10));
    ld16(s + (size_t)64 * KDIM, lds + ldsOff + 8192 + (wid << 10));
  };

#define READ_A(dst_, ab_)                                                     \
  _Pragma("unroll") for (int m = 0; m < 4; ++m) {                             \
    dst_[0][m] = *(const bf16x8*)((ab_) + aRowOff + m * 2048 + c0);           \
    dst_[1][m] = *(const bf16x8*)((ab_) + aRowOff + m * 2048 + c1);           \
  }
#define READ_B(dst_, bb_)                                                     \
  _Pragma("unroll") for (int n = 0; n < 2; ++n) {                             \
    dst_[0][n] = *(const bf16x8*)((bb_) + bRowOff + n * 2048 + c0);           \
    dst_[1][n] = *(const bf16x8*)((bb_) + bRowOff + n * 2048 + c1);           \
  }
#define MFMA16(mh_, g_, afr_, bsrc_)                                          \
  __builtin_amdgcn_s_setprio(1);                                              \
  _Pragma("unroll") for (int m = 0; m < 4; ++m)                               \
    _Pragma("unroll") for (int n = 0; n < 2; ++n) {                           \
      acc[mh_][g_][m][n] = __builtin_amdgcn_mfma_f32_16x16x32_bf16(           \
          afr_[0][m], bsrc_[0][n], acc[mh_][g_][m][n], 0, 0, 0);              \
      acc[mh_][g_][m][n] = __builtin_amdgcn_mfma_f32_16x16x32_bf16(           \
          afr_[1][m], bsrc_[1][n], acc[mh_][g_][m][n], 0, 0, 0);              \
    }                                                                         \
  __builtin_amdgcn_s_setprio(0);
#define LGKM(n_)                                                              \
  asm volatile("s_waitcnt lgkmcnt(" #n_ ")" ::: "memory");                    \
  __builtin_amdgcn_sched_barrier(0);
#define SCHED0 __builtin_amdgcn_sched_barrier(0)

  // prologue: tile0 (A-lo,B0,A-hi,B1) + tile1 (A-lo,B0); wait tile0 landed
  stageU(aSrc, 0, 0);
  stageU(b0Src, 32768, 0);
  stageU(aSrc + (size_t)128 * KDIM, 16384, 0);
  stageU(b1Src, 49152, 0);
  stageU(aSrc, 65536, 64);
  stageU(b0Src, 65536 + 32768, 64);
  asm volatile("s_waitcnt vmcnt(4)" ::: "memory");   // tile0's 8 loads retired
  __builtin_amdgcn_s_barrier();

  bf16x8 afX[2][4], b0X[2][2], b1X[2][2];
  bf16x8 afY[2][4], b0Y[2][2], b1Y[2][2];
  // initial reads for tile 0 into set X — order pinned: af(8), b0(4), b1(4)
  READ_A(afX, lds);          SCHED0;
  READ_B(b0X, lds + 32768);  SCHED0;
  READ_B(b1X, lds + 49152);  SCHED0;

// One K-tile. CUR set feeds this tile's 64 MFMAs; tail reads fill NXT set
// (issued BEFORE the deferred MFMA clusters — no WAR, overlap guaranteed).
#define TILE(tt_, cb_, cnb_, AF, B0R, B1R, AFN, B0N, B1N)                      \
  {                                                                            \
    const int t1 = ((tt_) + 1 < NT) ? (tt_) + 1 : NT - 1;                      \
    const int t2 = ((tt_) + 2 < NT) ? (tt_) + 2 : NT - 1;                      \
    const int k1b = t1 << 6, k2b = t2 << 6;                                    \
    const char* base = lds + (cb_);                                            \
    const char* nbase = lds + (cnb_);                                          \
    /* S1 */                                                                   \
    LGKM(4);                                   /* AF_lo + B0R ready */         \
    stageU(aSrc + (size_t)128 * KDIM, (cnb_) + 16384, k1b); /* A-hi(t+1) */    \
    stageU(b1Src, (cnb_) + 49152, k1b);                     /* B1  (t+1) */    \
    MFMA16(0, 0, AF, B0R);                                                     \
    LGKM(0);                                   /* B1R ready */                 \
    MFMA16(0, 1, AF, B1R);                                                     \
    READ_A(AF, base + 16384); SCHED0;          /* af_hi(t), WAR-ordered */     \
    __builtin_amdgcn_s_barrier();              /* BAR_B */                     \
    LGKM(0);                                   /* af_hi ready */               \
    /* S2 */                                                                   \
    stageU(aSrc, (cb_), k2b);                  /* A-lo(t+2) */                 \
    stageU(b0Src, (cb_) + 32768, k2b);         /* B0  (t+2) */                 \
    asm volatile("s_waitcnt vmcnt(4)" ::: "memory"); /* t+1 fully landed */    \
    SCHED0;                                                                    \
    __builtin_amdgcn_s_barrier();              /* BAR_A */                     \
    READ_A(AFN, nbase);           SCHED0;      /* tail reads -> NXT set */     \
    READ_B(B0N, nbase + 32768);   SCHED0;                                      \
    READ_B(B1N, nbase + 49152);   SCHED0;                                      \
    MFMA16(1, 1, AF, B1R);                     /* drain under matrix busy */   \
    MFMA16(1, 0, AF, B0R);                                                     \
  }

  for (int tt = 0; tt < NT; tt += 2) {
    TILE(tt,     0,     65536, afX, b0X, b1X, afY, b0Y, b1Y);
    TILE(tt + 1, 65536, 0,     afY, b0Y, b1Y, afX, b0X, b1X);
  }
  asm volatile("s_waitcnt vmcnt(0) lgkmcnt(0)" ::: "memory");  // drain tail
#undef TILE
#undef READ_A
#undef READ_B
#undef MFMA16
#undef LGKM
#undef SCHED0

  const int fq = (lane >> 4) << 2;
  if constexpr (GATED) {
    unsigned short* Z = (unsigned short*)outp;        // [*, 8192]
#pragma unroll
    for (int mh = 0; mh < 2; ++mh)
#pragma unroll
      for (int m = 0; m < 4; ++m)
#pragma unroll
        for (int n = 0; n < 2; ++n) {
          const size_t row = m0 + (mh << 7) + (wr << 6) + (m << 4) + fq;
          const size_t col = ((size_t)nb << 7) + (wc << 5) + (n << 4) + fr;
#pragma unroll
          for (int rr = 0; rr < 4; ++rr) {
            const float y0 = acc[mh][0][m][n][rr];
            const float y1 = acc[mh][1][m][n][rr];
            Z[(row + rr) * 8192 + col] = f2bf(gelu_tanh(y0) * y1);
          }
        }
  } else {
    float* O = (float*)outp;                          // [*, 2048]
#pragma unroll
    for (int mh = 0; mh < 2; ++mh)
#pragma unroll
      for (int g = 0; g < 2; ++g)
#pragma unroll
        for (int m = 0; m < 4; ++m)
#pragma unroll
          for (int n = 0; n < 2; ++n) {
            const size_t row = m0 + (mh << 7) + (wr << 6) + (m << 4) + fq;
            const size_t col = ((size_t)nb << 8) + (g << 7) + (wc << 5) + (n << 4) + fr;
#pragma unroll
            for (int rr = 0; rr < 4; ++rr)
              O[(row + rr) * 2048 + col] = acc[mh][g][m][n][rr];
          }
  }
}

extern "C" void kernel_launch(void* const* d_in, const int* in_sizes, int n_in,
                              void* d_out, int out_size, void* d_ws, size_t ws_size,
                              hipStream_t stream) {
  const float* x     = (const float*)d_in[0];
  const float* gamma = (const float*)d_in[1];
  const float* beta  = (const float*)d_in[2];
  const float* k1    = (const float*)d_in[3];   // [2048][2][8192] = [2048][16384]
  const float* k2    = (const float*)d_in[4];   // [8192][2048]
  float* out = (float*)d_out;

  const size_t H = 2048, I = 8192, M = 8192;
  unsigned short* k1T = (unsigned short*)d_ws;     // [16384][2048] bf16 (w0^T then w1^T)
  unsigned short* k2T = k1T + 2 * I * H;           // [2048][8192]  bf16
  unsigned short* lnb = k2T + H * I;               // [8192][2048]  bf16
  unsigned short* zb  = lnb + M * H;               // [Mc][8192]    bf16

  const size_t fixedB = (2 * I * H + H * I + M * H) * 2;  // 134.2 MB
  int nc = 1;
  while (nc < 32 && fixedB + (M / nc) * I * 2 > ws_size) nc <<= 1;

  transpose_cast_kernel<<<dim3(H / 32, (2 * I) / 32), 256, 0, stream>>>(
      k1, k1T, (int)H, (int)(2 * I));
  transpose_cast_kernel<<<dim3(I / 32, H / 32), 256, 0, stream>>>(
      k2, k2T, (int)I, (int)H);
  ln_kernel<<<dim3((unsigned)M), 256, 0, stream>>>(x, gamma, beta, lnb);

  const size_t Mc = M / nc;
  const int mC = (int)(Mc / 256);
  for (int c = 0; c < nc; ++c) {
    gemm8p<2048, true><<<dim3((unsigned)(mC * 64)), 512, 0, stream>>>(
        lnb + c * Mc * H, k1T, k1T + (size_t)8192 * 2048, zb, mC);
    gemm8p<8192, false><<<dim3((unsigned)(mC * 8)), 512, 0, stream>>>(
        zb, k2T, k2T + (size_t)128 * 8192, out + c * Mc * H, mC);
  }
}

// Round 11
// 1104.364 us; speedup vs baseline: 2.3242x; 2.3242x over previous
//
#include <hip/hip_runtime.h>
#include <hip/hip_bf16.h>

#define DEVINL __device__ __forceinline__

typedef __attribute__((ext_vector_type(8))) __bf16 bf16x8;
typedef __attribute__((ext_vector_type(4))) float f32x4;
typedef __attribute__((ext_vector_type(4))) unsigned short us4;

DEVINL unsigned short f2bf(float f) {
  union { float f; unsigned int u; } c;
  c.f = f;
  unsigned int u = c.u;
  u += 0x7fffu + ((u >> 16) & 1u);   // RNE
  return (unsigned short)(u >> 16);
}

// jax.nn.gelu(approximate=True) = x * sigmoid(2*sqrt(2/pi)*(x + 0.044715 x^3))
DEVINL float gelu_tanh(float x) {
  float t = 1.5957691216057308f * x * __builtin_fmaf(0.044715f, x * x, 1.0f);
  return x / (1.0f + __expf(-t));
}

DEVINL void ld16(const void* g, void* l) {
  __builtin_amdgcn_global_load_lds(
      (const __attribute__((address_space(1))) void*)g,
      (__attribute__((address_space(3))) void*)l, 16, 0, 0);
}

// ---------------- transpose + fp32->bf16 cast: in[R][C] f32 -> out[C][R] bf16
__global__ __launch_bounds__(256) void transpose_cast_kernel(
    const float* __restrict__ in, unsigned short* __restrict__ out, int R, int C) {
  __shared__ float tile[32][33];
  const int t = threadIdx.x;
  const int r0 = blockIdx.x << 5, c0 = blockIdx.y << 5;
  const int tr = t >> 3, tc = (t & 7) << 2;
  const float4 v = *(const float4*)(in + (size_t)(r0 + tr) * C + c0 + tc);
  tile[tr][tc] = v.x; tile[tr][tc + 1] = v.y;
  tile[tr][tc + 2] = v.z; tile[tr][tc + 3] = v.w;
  __syncthreads();
  us4 o;
  o[0] = f2bf(tile[tc + 0][tr]);
  o[1] = f2bf(tile[tc + 1][tr]);
  o[2] = f2bf(tile[tc + 2][tr]);
  o[3] = f2bf(tile[tc + 3][tr]);
  *(us4*)(out + (size_t)(c0 + tr) * R + r0 + tc) = o;
}

// ---------------- LayerNorm: x[8192][2048] f32 -> ln bf16
__global__ __launch_bounds__(256) void ln_kernel(
    const float* __restrict__ x, const float* __restrict__ gamma,
    const float* __restrict__ beta, unsigned short* __restrict__ out) {
  constexpr int H = 2048;
  const int t = threadIdx.x;
  const size_t row = blockIdx.x;
  const float4* xr = (const float4*)(x + row * H);
  const float4 a = xr[t], b = xr[t + 256];
  float s  = a.x + a.y + a.z + a.w + b.x + b.y + b.z + b.w;
  float s2 = a.x*a.x + a.y*a.y + a.z*a.z + a.w*a.w
           + b.x*b.x + b.y*b.y + b.z*b.z + b.w*b.w;
#pragma unroll
  for (int o = 32; o > 0; o >>= 1) { s += __shfl_xor(s, o); s2 += __shfl_xor(s2, o); }
  __shared__ float red[8];
  const int wid = t >> 6, lane = t & 63;
  if (lane == 0) { red[wid] = s; red[4 + wid] = s2; }
  __syncthreads();
  s  = red[0] + red[1] + red[2] + red[3];
  s2 = red[4] + red[5] + red[6] + red[7];
  const float mean = s * (1.0f / H);
  const float rstd = rsqrtf(s2 * (1.0f / H) - mean * mean + 1e-6f);
  const float4 g0 = ((const float4*)gamma)[t], g1 = ((const float4*)gamma)[t + 256];
  const float4 c0 = ((const float4*)beta)[t],  c1 = ((const float4*)beta)[t + 256];
  us4 o0, o1;
  o0[0] = f2bf((a.x - mean) * rstd * g0.x + c0.x);
  o0[1] = f2bf((a.y - mean) * rstd * g0.y + c0.y);
  o0[2] = f2bf((a.z - mean) * rstd * g0.z + c0.z);
  o0[3] = f2bf((a.w - mean) * rstd * g0.w + c0.w);
  o1[0] = f2bf((b.x - mean) * rstd * g1.x + c1.x);
  o1[1] = f2bf((b.y - mean) * rstd * g1.y + c1.y);
  o1[2] = f2bf((b.z - mean) * rstd * g1.z + c1.z);
  o1[3] = f2bf((b.w - mean) * rstd * g1.w + c1.w);
  *(us4*)(out + row * H + (size_t)t * 4) = o0;
  *(us4*)(out + row * H + 1024 + (size_t)t * 4) = o1;
}

// ---------------- 256-wide MFMA GEMM, B fragments DIRECT from L2 (no B LDS)
// A [*][KDIM] bf16 K-contig, staged via global_load_lds into a 4-slot LDS ring
// (32KB/slot, slot = tile&3; stage t+2 never collides with reads of t).
// B^T row panels are L2-resident (lockstep block map) -> B fragments are loaded
// straight global->VGPR: frag[ks][n] = B^T[wc*32+n*16+fr][k0+ks*32+l16*8..+8]
// (identical math to the LDS path after the swizzle algebra cancels).
// Per tile: 16 A ds_reads (LDS 1536 cyc/CU) < 64 MFMA (2484 cyc/SIMD):
//  top:   LOAD_B(t+1) -> alternate reg set (8 global dwordx4, L2 hits)
//         READ af_lo(t) (8 ds_read_b128)
//  mid:   MFMA(0,0),(0,1);  READ af_hi(t) + stage A(t+2) (drain UNDER MFMA)
//  tail:  MFMA(1,1),(1,0);  vmcnt(12); BAR  (single barrier/tile)
// vmcnt ledger (12 ops/tile = lB 8 + sA 4): compiler auto-waits B values
// (retires lB(t), leaves 12); manual vmcnt(12) retires sA(t+1) -> next tile's
// A reads are after BAR => visible. Registers: acc 128 AGPR + ~115 VGPR
// (af 32 reused lo/hi, B 2x32, addr) <= 256 unified -> no spill (r10 lesson).
template<int KDIM, bool GATED>
__global__ __launch_bounds__(512, 2) void gemm_bd(
    const unsigned short* __restrict__ Amat,
    const unsigned short* __restrict__ Bm0,
    const unsigned short* __restrict__ Bm1,
    void* __restrict__ outp, int mCount) {
  constexpr int NT = KDIM / 64;
  __shared__ char lds[131072];                          // 4 slots x 32KB
  const int t = threadIdx.x, lane = t & 63, wid = t >> 6;
  const int wr = wid >> 2, wc = wid & 3;                // 2 x 4 waves
  const int bid = (int)blockIdx.x;
  int mb, nb;
  if (GATED && mCount >= 8) {
    // L2-lockstep 2D chunk map: per XCD, 32 concurrent blocks = 8 mb x 4 nb.
    const int xcd = bid & 7, l = bid >> 3;
    const int g = l >> 5, l32 = l & 31;
    const int mchunks = mCount >> 3;
    const int quad = g / mchunks, mch = g % mchunks;
    mb = (mch << 3) | (l32 & 7);
    nb = (xcd << 3) | (quad << 2) | (l32 >> 3);
  } else {
    // gemm2: one nb per XCD (B panel 4MB L2-resident)
    const int nwg = (int)gridDim.x, q = nwg >> 3;
    const int wg = (bid & 7) * q + (bid >> 3);
    mb = wg % mCount; nb = wg / mCount;
  }
  const size_t m0 = (size_t)mb << 8;
  const size_t nrow = (size_t)nb * (GATED ? 128 : 256);
  const unsigned short* aSrc  = Amat + m0 * KDIM;
  const unsigned short* b0Src = Bm0 + nrow * KDIM;
  const unsigned short* b1Src = Bm1 + nrow * KDIM;

  // A staging: slot = 32KB = 256 rows x 64k x 2B; 4 ld16/thread (one per 64-row unit)
  const int srow = (wid << 3) + (lane >> 3);            // 0..63
  const int sOff = srow * KDIM + (((lane & 7) ^ (srow & 7)) << 3);  // pre-swizzled src

  // A fragment read geometry (swizzled, unchanged from verified kernel)
  const int fr = lane & 15, l16 = lane >> 4;
  const int c0 = (l16 ^ (fr & 7)) << 4;
  const int c1 = ((4 | l16) ^ (fr & 7)) << 4;
  const int aRowOff = ((wr << 6) + fr) << 7;

  // B direct-load geometry
  const size_t bOff = (size_t)((wc << 5) + fr) * KDIM + (size_t)(l16 << 3);

  f32x4 acc[2][2][4][2] = {};                           // [mh][g][m][n]

  auto stageA = [&](int slotBase, int k0) {
    const unsigned short* s = aSrc + sOff + k0;
    char* d = lds + slotBase + (wid << 10);
    ld16(s, d);
    ld16(s + (size_t)64 * KDIM, d + 8192);
    ld16(s + (size_t)128 * KDIM, d + 16384);
    ld16(s + (size_t)192 * KDIM, d + 24576);
  };

#define READ_A(ab_)                                                           \
  _Pragma("unroll") for (int m = 0; m < 4; ++m) {                             \
    af[0][m] = *(const bf16x8*)((ab_) + aRowOff + m * 2048 + c0);             \
    af[1][m] = *(const bf16x8*)((ab_) + aRowOff + m * 2048 + c1);             \
  }
#define LOAD_B(d0_, d1_, k0_)                                                 \
  _Pragma("unroll") for (int n = 0; n < 2; ++n) {                             \
    const unsigned short* p0 = b0Src + bOff + (size_t)(n * 16) * KDIM + (k0_);\
    const unsigned short* p1 = b1Src + bOff + (size_t)(n * 16) * KDIM + (k0_);\
    d0_[0][n] = *(const bf16x8*)(p0);                                         \
    d0_[1][n] = *(const bf16x8*)(p0 + 32);                                    \
    d1_[0][n] = *(const bf16x8*)(p1);                                         \
    d1_[1][n] = *(const bf16x8*)(p1 + 32);                                    \
  }
#define MFMA16(mh_, g_, bsrc_)                                                \
  _Pragma("unroll") for (int m = 0; m < 4; ++m)                               \
    _Pragma("unroll") for (int n = 0; n < 2; ++n) {                           \
      acc[mh_][g_][m][n] = __builtin_amdgcn_mfma_f32_16x16x32_bf16(           \
          af[0][m], bsrc_[0][n], acc[mh_][g_][m][n], 0, 0, 0);                \
      acc[mh_][g_][m][n] = __builtin_amdgcn_mfma_f32_16x16x32_bf16(           \
          af[1][m], bsrc_[1][n], acc[mh_][g_][m][n], 0, 0, 0);                \
    }
#define SCHED0 __builtin_amdgcn_sched_barrier(0)

  bf16x8 af[2][4];
  bf16x8 b0X[2][2], b1X[2][2], b0Y[2][2], b1Y[2][2];

  // prologue: stage A(0)->slot0, load B(0)->X, stage A(1)->slot1
  stageA(0, 0);
  LOAD_B(b0X, b1X, 0);
  stageA(32768, NT > 1 ? 64 : 0);
  asm volatile("s_waitcnt vmcnt(12)" ::: "memory");   // A(0) retired
  __builtin_amdgcn_s_barrier();

// One K-tile. BC = this tile's B regs; BN = next tile's (loaded at top, no WAR).
#define TILE(tt_, SL_, SL2_, BC0, BC1, BN0, BN1)                               \
  {                                                                            \
    const int t1 = ((tt_) + 1 < NT) ? (tt_) + 1 : NT - 1;                      \
    const int t2 = ((tt_) + 2 < NT) ? (tt_) + 2 : NT - 1;                      \
    LOAD_B(BN0, BN1, t1 << 6);                                                 \
    READ_A(lds + (SL_) * 32768);            /* af_lo(t) */                     \
    SCHED0;                                                                    \
    __builtin_amdgcn_s_setprio(1);                                             \
    MFMA16(0, 0, BC0);                                                         \
    MFMA16(0, 1, BC1);                                                         \
    __builtin_amdgcn_s_setprio(0);                                             \
    SCHED0;                                                                    \
    READ_A(lds + (SL_) * 32768 + 16384);    /* af_hi(t): drains under MFMA */  \
    stageA((SL2_) * 32768, t2 << 6);        /* A(t+2) -> free slot */          \
    SCHED0;                                                                    \
    __builtin_amdgcn_s_setprio(1);                                             \
    MFMA16(1, 1, BC1);                                                         \
    MFMA16(1, 0, BC0);                                                         \
    __builtin_amdgcn_s_setprio(0);                                             \
    SCHED0;                                                                    \
    asm volatile("s_waitcnt vmcnt(12)" ::: "memory");  /* sA(t+1) retired */   \
    __builtin_amdgcn_s_barrier();           /* A(t+1) visible to all waves */  \
  }

  for (int tt = 0; tt < NT; tt += 4) {
    TILE(tt,     0, 2, b0X, b1X, b0Y, b1Y);
    TILE(tt + 1, 1, 3, b0Y, b1Y, b0X, b1X);
    TILE(tt + 2, 2, 0, b0X, b1X, b0Y, b1Y);
    TILE(tt + 3, 3, 1, b0Y, b1Y, b0X, b1X);
  }
  asm volatile("s_waitcnt vmcnt(0) lgkmcnt(0)" ::: "memory");  // drain tail
#undef TILE
#undef READ_A
#undef LOAD_B
#undef MFMA16
#undef SCHED0

  const int fq = (lane >> 4) << 2;
  if constexpr (GATED) {
    unsigned short* Z = (unsigned short*)outp;        // [*, 8192]
#pragma unroll
    for (int mh = 0; mh < 2; ++mh)
#pragma unroll
      for (int m = 0; m < 4; ++m)
#pragma unroll
        for (int n = 0; n < 2; ++n) {
          const size_t row = m0 + (mh << 7) + (wr << 6) + (m << 4) + fq;
          const size_t col = ((size_t)nb << 7) + (wc << 5) + (n << 4) + fr;
#pragma unroll
          for (int rr = 0; rr < 4; ++rr) {
            const float y0 = acc[mh][0][m][n][rr];
            const float y1 = acc[mh][1][m][n][rr];
            Z[(row + rr) * 8192 + col] = f2bf(gelu_tanh(y0) * y1);
          }
        }
  } else {
    float* O = (float*)outp;                          // [*, 2048]
#pragma unroll
    for (int mh = 0; mh < 2; ++mh)
#pragma unroll
      for (int g = 0; g < 2; ++g)
#pragma unroll
        for (int m = 0; m < 4; ++m)
#pragma unroll
          for (int n = 0; n < 2; ++n) {
            const size_t row = m0 + (mh << 7) + (wr << 6) + (m << 4) + fq;
            const size_t col = ((size_t)nb << 8) + (g << 7) + (wc << 5) + (n << 4) + fr;
#pragma unroll
            for (int rr = 0; rr < 4; ++rr)
              O[(row + rr) * 2048 + col] = acc[mh][g][m][n][rr];
          }
  }
}

extern "C" void kernel_launch(void* const* d_in, const int* in_sizes, int n_in,
                              void* d_out, int out_size, void* d_ws, size_t ws_size,
                              hipStream_t stream) {
  const float* x     = (const float*)d_in[0];
  const float* gamma = (const float*)d_in[1];
  const float* beta  = (const float*)d_in[2];
  const float* k1    = (const float*)d_in[3];   // [2048][2][8192] = [2048][16384]
  const float* k2    = (const float*)d_in[4];   // [8192][2048]
  float* out = (float*)d_out;

  const size_t H = 2048, I = 8192, M = 8192;
  unsigned short* k1T = (unsigned short*)d_ws;     // [16384][2048] bf16 (w0^T then w1^T)
  unsigned short* k2T = k1T + 2 * I * H;           // [2048][8192]  bf16
  unsigned short* lnb = k2T + H * I;               // [8192][2048]  bf16
  unsigned short* zb  = lnb + M * H;               // [Mc][8192]    bf16

  const size_t fixedB = (2 * I * H + H * I + M * H) * 2;  // 134.2 MB
  int nc = 1;
  while (nc < 32 && fixedB + (M / nc) * I * 2 > ws_size) nc <<= 1;

  transpose_cast_kernel<<<dim3(H / 32, (2 * I) / 32), 256, 0, stream>>>(
      k1, k1T, (int)H, (int)(2 * I));
  transpose_cast_kernel<<<dim3(I / 32, H / 32), 256, 0, stream>>>(
      k2, k2T, (int)I, (int)H);
  ln_kernel<<<dim3((unsigned)M), 256, 0, stream>>>(x, gamma, beta, lnb);

  const size_t Mc = M / nc;
  const int mC = (int)(Mc / 256);
  for (int c = 0; c < nc; ++c) {
    gemm_bd<2048, true><<<dim3((unsigned)(mC * 64)), 512, 0, stream>>>(
        lnb + c * Mc * H, k1T, k1T + (size_t)8192 * 2048, zb, mC);
    gemm_bd<8192, false><<<dim3((unsigned)(mC * 8)), 512, 0, stream>>>(
        zb, k2T, k2T + (size_t)128 * 8192, out + c * Mc * H, mC);
  }
}

// Round 12
// 770.979 us; speedup vs baseline: 3.3293x; 1.4324x over previous
//
#include <hip/hip_runtime.h>
#include <hip/hip_bf16.h>

#define DEVINL __device__ __forceinline__

typedef __attribute__((ext_vector_type(8))) __bf16 bf16x8;
typedef __attribute__((ext_vector_type(4))) float f32x4;
typedef __attribute__((ext_vector_type(4))) unsigned short us4;

DEVINL unsigned short f2bf(float f) {
  union { float f; unsigned int u; } c;
  c.f = f;
  unsigned int u = c.u;
  u += 0x7fffu + ((u >> 16) & 1u);   // RNE
  return (unsigned short)(u >> 16);
}

// jax.nn.gelu(approximate=True) = x * sigmoid(2*sqrt(2/pi)*(x + 0.044715 x^3))
DEVINL float gelu_tanh(float x) {
  float t = 1.5957691216057308f * x * __builtin_fmaf(0.044715f, x * x, 1.0f);
  return x / (1.0f + __expf(-t));
}

DEVINL void ld16(const void* g, void* l) {
  __builtin_amdgcn_global_load_lds(
      (const __attribute__((address_space(1))) void*)g,
      (__attribute__((address_space(3))) void*)l, 16, 0, 0);
}

// ---------------- transpose + fp32->bf16 cast: in[R][C] f32 -> out[C][R] bf16
__global__ __launch_bounds__(256) void transpose_cast_kernel(
    const float* __restrict__ in, unsigned short* __restrict__ out, int R, int C) {
  __shared__ float tile[32][33];
  const int t = threadIdx.x;
  const int r0 = blockIdx.x << 5, c0 = blockIdx.y << 5;
  const int tr = t >> 3, tc = (t & 7) << 2;
  const float4 v = *(const float4*)(in + (size_t)(r0 + tr) * C + c0 + tc);
  tile[tr][tc] = v.x; tile[tr][tc + 1] = v.y;
  tile[tr][tc + 2] = v.z; tile[tr][tc + 3] = v.w;
  __syncthreads();
  us4 o;
  o[0] = f2bf(tile[tc + 0][tr]);
  o[1] = f2bf(tile[tc + 1][tr]);
  o[2] = f2bf(tile[tc + 2][tr]);
  o[3] = f2bf(tile[tc + 3][tr]);
  *(us4*)(out + (size_t)(c0 + tr) * R + r0 + tc) = o;
}

// ---------------- LayerNorm: x[8192][2048] f32 -> ln bf16
__global__ __launch_bounds__(256) void ln_kernel(
    const float* __restrict__ x, const float* __restrict__ gamma,
    const float* __restrict__ beta, unsigned short* __restrict__ out) {
  constexpr int H = 2048;
  const int t = threadIdx.x;
  const size_t row = blockIdx.x;
  const float4* xr = (const float4*)(x + row * H);
  const float4 a = xr[t], b = xr[t + 256];
  float s  = a.x + a.y + a.z + a.w + b.x + b.y + b.z + b.w;
  float s2 = a.x*a.x + a.y*a.y + a.z*a.z + a.w*a.w
           + b.x*b.x + b.y*b.y + b.z*b.z + b.w*b.w;
#pragma unroll
  for (int o = 32; o > 0; o >>= 1) { s += __shfl_xor(s, o); s2 += __shfl_xor(s2, o); }
  __shared__ float red[8];
  const int wid = t >> 6, lane = t & 63;
  if (lane == 0) { red[wid] = s; red[4 + wid] = s2; }
  __syncthreads();
  s  = red[0] + red[1] + red[2] + red[3];
  s2 = red[4] + red[5] + red[6] + red[7];
  const float mean = s * (1.0f / H);
  const float rstd = rsqrtf(s2 * (1.0f / H) - mean * mean + 1e-6f);
  const float4 g0 = ((const float4*)gamma)[t], g1 = ((const float4*)gamma)[t + 256];
  const float4 c0 = ((const float4*)beta)[t],  c1 = ((const float4*)beta)[t + 256];
  us4 o0, o1;
  o0[0] = f2bf((a.x - mean) * rstd * g0.x + c0.x);
  o0[1] = f2bf((a.y - mean) * rstd * g0.y + c0.y);
  o0[2] = f2bf((a.z - mean) * rstd * g0.z + c0.z);
  o0[3] = f2bf((a.w - mean) * rstd * g0.w + c0.w);
  o1[0] = f2bf((b.x - mean) * rstd * g1.x + c1.x);
  o1[1] = f2bf((b.y - mean) * rstd * g1.y + c1.y);
  o1[2] = f2bf((b.z - mean) * rstd * g1.z + c1.z);
  o1[3] = f2bf((b.w - mean) * rstd * g1.w + c1.w);
  *(us4*)(out + row * H + (size_t)t * 4) = o0;
  *(us4*)(out + row * H + 1024 + (size_t)t * 4) = o1;
}

// ---------------- 256-wide MFMA GEMM, m-group-interleaved LDS reads
// A [*][KDIM] bf16 K-contig. Bm0/Bm1: B^T row panels (K-contig).
// GATED: block tile = 256x128, two B mats (gelu(y0)*y1 -> bf16 Z[*,8192])
// else : block tile = 256x256, Bm1 = Bm0 + 128 rows (f32 Out[*,2048])
// LDS slots/buffer: A-lo | A-hi | B0 | B1 (16K each); double buffered = 128KB.
// Every ds_read is interleaved into an MFMA cluster at the point its target
// register dies (af[*][m] dead after group m of the last cluster using it):
//  TOP:  LGKM(0) [tail reads of t]; stage A-hi(t+1),B1(t+1);
//        C(0,0) [16]; {C(0,1,m) [4]; read af_hi[m](t) [2]}x4;
//        LGKM(0) [af_hi drained - airtight ledger]; BAR_B;
//        stage A-lo(t+2),B0(t+2); vmcnt(4); BAR_A  [tile t+1 visible].
//  TAIL: C(1,1) [16, af_hi x b1r]; read b1(t+1) [b1r dead];
//        {C(1,0,m); read af_lo[m](t+1)}x4; read b0(t+1) [b0r dead last].
// SCHED0 pins each group (compiler would sink reads). 2 barriers/tile.
// Ledger: every slot's reader-drain precedes >=2 barriers before its restage;
// vmcnt(4): 12 in flight, retire 8 oldest = tile t+1 complete (as r9).
// Registers: acc 128 AGPR + ~110 VGPR <= 256 unified -> no spill (r10 lesson).
template<int KDIM, bool GATED>
__global__ __launch_bounds__(512, 2) void gemm8p(
    const unsigned short* __restrict__ Amat,
    const unsigned short* __restrict__ Bm0,
    const unsigned short* __restrict__ Bm1,
    void* __restrict__ outp, int mCount) {
  constexpr int NT = KDIM / 64;
  __shared__ char lds[131072];
  const int t = threadIdx.x, lane = t & 63, wid = t >> 6;
  const int wr = wid >> 2, wc = wid & 3;                // 2 x 4 waves
  const int bid = (int)blockIdx.x;
  int mb, nb;
  if (GATED && mCount >= 8) {
    // L2-lockstep 2D chunk map: per XCD, 32 concurrent blocks = 8 mb x 4 nb.
    const int xcd = bid & 7, l = bid >> 3;
    const int g = l >> 5, l32 = l & 31;
    const int mchunks = mCount >> 3;
    const int quad = g / mchunks, mch = g % mchunks;
    mb = (mch << 3) | (l32 & 7);
    nb = (xcd << 3) | (quad << 2) | (l32 >> 3);
  } else {
    // gemm2: one nb per XCD (B panel 4MB L2-resident)
    const int nwg = (int)gridDim.x, q = nwg >> 3;
    const int wg = (bid & 7) * q + (bid >> 3);
    mb = wg % mCount; nb = wg / mCount;
  }
  const size_t m0 = (size_t)mb << 8;
  const size_t nrow = (size_t)nb * (GATED ? 128 : 256);
  const unsigned short* aSrc  = Amat + m0 * KDIM;
  const unsigned short* b0Src = Bm0 + nrow * KDIM;
  const unsigned short* b1Src = Bm1 + nrow * KDIM;

  // staging geometry: unit = 128 rows x 64 k x 2B = 16KB = 2 x ld16/thread
  const int srow = (wid << 3) + (lane >> 3);            // 0..63
  const int sOff = srow * KDIM + (((lane & 7) ^ (srow & 7)) << 3);  // pre-swizzled source

  // fragment read geometry
  const int fr = lane & 15, l16 = lane >> 4;
  const int c0 = (l16 ^ (fr & 7)) << 4;                 // ks=0 chunk byte-off (swizzled)
  const int c1 = ((4 | l16) ^ (fr & 7)) << 4;           // ks=1
  const int aRowOff = ((wr << 6) + fr) << 7;
  const int bRowOff = ((wc << 5) + fr) << 7;

  f32x4 acc[2][2][4][2] = {};                           // [mh][g][m][n]

  auto stageU = [&](const unsigned short* src, int ldsOff, int k0) {
    const unsigned short* s = src + sOff + k0;
    ld16(s, lds + ldsOff + (wid << 10));
    ld16(s + (size_t)64 * KDIM, lds + ldsOff + 8192 + (wid << 10));
  };

#define RD_AM(ab_, m_)                                                        \
  af[0][m_] = *(const bf16x8*)((ab_) + aRowOff + (m_) * 2048 + c0);           \
  af[1][m_] = *(const bf16x8*)((ab_) + aRowOff + (m_) * 2048 + c1);
#define READ_A(ab_)                                                           \
  { RD_AM(ab_, 0) RD_AM(ab_, 1) RD_AM(ab_, 2) RD_AM(ab_, 3) }
#define READ_B(dst_, bb_)                                                     \
  _Pragma("unroll") for (int n = 0; n < 2; ++n) {                             \
    dst_[0][n] = *(const bf16x8*)((bb_) + bRowOff + n * 2048 + c0);           \
    dst_[1][n] = *(const bf16x8*)((bb_) + bRowOff + n * 2048 + c1);           \
  }
#define MFMA_G(mh_, g_, m_, bsrc_)                                            \
  _Pragma("unroll") for (int n = 0; n < 2; ++n) {                             \
    acc[mh_][g_][m_][n] = __builtin_amdgcn_mfma_f32_16x16x32_bf16(            \
        af[0][m_], bsrc_[0][n], acc[mh_][g_][m_][n], 0, 0, 0);                \
    acc[mh_][g_][m_][n] = __builtin_amdgcn_mfma_f32_16x16x32_bf16(            \
        af[1][m_], bsrc_[1][n], acc[mh_][g_][m_][n], 0, 0, 0);                \
  }
#define MFMA_CL(mh_, g_, bsrc_)                                               \
  { MFMA_G(mh_, g_, 0, bsrc_) MFMA_G(mh_, g_, 1, bsrc_)                       \
    MFMA_G(mh_, g_, 2, bsrc_) MFMA_G(mh_, g_, 3, bsrc_) }
#define LGKM(n_)                                                              \
  asm volatile("s_waitcnt lgkmcnt(" #n_ ")" ::: "memory");                    \
  __builtin_amdgcn_sched_barrier(0);
#define SCHED0 __builtin_amdgcn_sched_barrier(0)

  // prologue: tile0 (A-lo,B0,A-hi,B1) + tile1 (A-lo,B0); wait tile0 landed
  stageU(aSrc, 0, 0);
  stageU(b0Src, 32768, 0);
  stageU(aSrc + (size_t)128 * KDIM, 16384, 0);
  stageU(b1Src, 49152, 0);
  stageU(aSrc, 65536, NT > 1 ? 64 : 0);
  stageU(b0Src, 65536 + 32768, NT > 1 ? 64 : 0);
  asm volatile("s_waitcnt vmcnt(4)" ::: "memory");   // tile0's 8 loads retired
  __builtin_amdgcn_s_barrier();

  bf16x8 af[2][4], b0r[2][2], b1r[2][2];
  // initial reads for tile 0 (same order as the steady-state tail)
  READ_B(b1r, lds + 49152);  SCHED0;
  READ_A(lds);               SCHED0;
  READ_B(b0r, lds + 32768);  SCHED0;

  for (int tt = 0; tt < NT; ++tt) {
    const int c = tt & 1, cn = c ^ 1;
    const int t1 = (tt + 1 < NT) ? tt + 1 : NT - 1;
    const int t2 = (tt + 2 < NT) ? tt + 2 : NT - 1;
    const int k1b = t1 << 6, k2b = t2 << 6;
    const int cb = c << 16, cnb = cn << 16;
    const char* base = lds + cb;
    const char* nbase = lds + cnb;
    const char* hib = base + 16384;

    // ---- TOP
    LGKM(0);                                    // af_lo,b0r,b1r(t) all in regs
    stageU(aSrc + (size_t)128 * KDIM, cnb + 16384, k1b);  // A-hi(t+1)
    stageU(b1Src, cnb + 49152, k1b);                      // B1(t+1)
    __builtin_amdgcn_s_setprio(1);
    MFMA_CL(0, 0, b0r);                         // af_lo x b0r
    // (0,1) interleaved with af_hi reads (af_lo[m] dies after its group)
    MFMA_G(0, 1, 0, b1r); RD_AM(hib, 0) SCHED0;
    MFMA_G(0, 1, 1, b1r); RD_AM(hib, 1) SCHED0;
    MFMA_G(0, 1, 2, b1r); RD_AM(hib, 2) SCHED0;
    MFMA_G(0, 1, 3, b1r); RD_AM(hib, 3) SCHED0;
    __builtin_amdgcn_s_setprio(0);
    LGKM(0);                                    // af_hi drained (airtight)
    __builtin_amdgcn_s_barrier();               // BAR_B
    stageU(aSrc, cb, k2b);                      // A-lo(t+2)
    stageU(b0Src, cb + 32768, k2b);             // B0(t+2)
    asm volatile("s_waitcnt vmcnt(4)" ::: "memory");  // tile t+1 fully landed
    SCHED0;
    __builtin_amdgcn_s_barrier();               // BAR_A — t+1 visible to all

    // ---- TAIL: MFMA with next-tile reads slotted at register death points
    __builtin_amdgcn_s_setprio(1);
    MFMA_CL(1, 1, b1r);                         // af_hi x b1r; b1r dead
    READ_B(b1r, nbase + 49152); SCHED0;         // b1(t+1)
    MFMA_G(1, 0, 0, b0r); RD_AM(nbase, 0) SCHED0;  // af_lo[m](t+1)
    MFMA_G(1, 0, 1, b0r); RD_AM(nbase, 1) SCHED0;
    MFMA_G(1, 0, 2, b0r); RD_AM(nbase, 2) SCHED0;
    MFMA_G(1, 0, 3, b0r); RD_AM(nbase, 3) SCHED0;
    __builtin_amdgcn_s_setprio(0);
    READ_B(b0r, nbase + 32768); SCHED0;         // b0(t+1); b0r dead last
  }
  asm volatile("s_waitcnt vmcnt(0) lgkmcnt(0)" ::: "memory");  // drain tail
#undef RD_AM
#undef READ_A
#undef READ_B
#undef MFMA_G
#undef MFMA_CL
#undef LGKM
#undef SCHED0

  const int fq = (lane >> 4) << 2;
  if constexpr (GATED) {
    unsigned short* Z = (unsigned short*)outp;        // [*, 8192]
#pragma unroll
    for (int mh = 0; mh < 2; ++mh)
#pragma unroll
      for (int m = 0; m < 4; ++m)
#pragma unroll
        for (int n = 0; n < 2; ++n) {
          const size_t row = m0 + (mh << 7) + (wr << 6) + (m << 4) + fq;
          const size_t col = ((size_t)nb << 7) + (wc << 5) + (n << 4) + fr;
#pragma unroll
          for (int rr = 0; rr < 4; ++rr) {
            const float y0 = acc[mh][0][m][n][rr];
            const float y1 = acc[mh][1][m][n][rr];
            Z[(row + rr) * 8192 + col] = f2bf(gelu_tanh(y0) * y1);
          }
        }
  } else {
    float* O = (float*)outp;                          // [*, 2048]
#pragma unroll
    for (int mh = 0; mh < 2; ++mh)
#pragma unroll
      for (int g = 0; g < 2; ++g)
#pragma unroll
        for (int m = 0; m < 4; ++m)
#pragma unroll
          for (int n = 0; n < 2; ++n) {
            const size_t row = m0 + (mh << 7) + (wr << 6) + (m << 4) + fq;
            const size_t col = ((size_t)nb << 8) + (g << 7) + (wc << 5) + (n << 4) + fr;
#pragma unroll
            for (int rr = 0; rr < 4; ++rr)
              O[(row + rr) * 2048 + col] = acc[mh][g][m][n][rr];
          }
  }
}

extern "C" void kernel_launch(void* const* d_in, const int* in_sizes, int n_in,
                              void* d_out, int out_size, void* d_ws, size_t ws_size,
                              hipStream_t stream) {
  const float* x     = (const float*)d_in[0];
  const float* gamma = (const float*)d_in[1];
  const float* beta  = (const float*)d_in[2];
  const float* k1    = (const float*)d_in[3];   // [2048][2][8192] = [2048][16384]
  const float* k2    = (const float*)d_in[4];   // [8192][2048]
  float* out = (float*)d_out;

  const size_t H = 2048, I = 8192, M = 8192;
  unsigned short* k1T = (unsigned short*)d_ws;     // [16384][2048] bf16 (w0^T then w1^T)
  unsigned short* k2T = k1T + 2 * I * H;           // [2048][8192]  bf16
  unsigned short* lnb = k2T + H * I;               // [8192][2048]  bf16
  unsigned short* zb  = lnb + M * H;               // [Mc][8192]    bf16

  const size_t fixedB = (2 * I * H + H * I + M * H) * 2;  // 134.2 MB
  int nc = 1;
  while (nc < 32 && fixedB + (M / nc) * I * 2 > ws_size) nc <<= 1;

  transpose_cast_kernel<<<dim3(H / 32, (2 * I) / 32), 256, 0, stream>>>(
      k1, k1T, (int)H, (int)(2 * I));
  transpose_cast_kernel<<<dim3(I / 32, H / 32), 256, 0, stream>>>(
      k2, k2T, (int)I, (int)H);
  ln_kernel<<<dim3((unsigned)M), 256, 0, stream>>>(x, gamma, beta, lnb);

  const size_t Mc = M / nc;
  const int mC = (int)(Mc / 256);
  for (int c = 0; c < nc; ++c) {
    gemm8p<2048, true><<<dim3((unsigned)(mC * 64)), 512, 0, stream>>>(
        lnb + c * Mc * H, k1T, k1T + (size_t)8192 * 2048, zb, mC);
    gemm8p<8192, false><<<dim3((unsigned)(mC * 8)), 512, 0, stream>>>(
        zb, k2T, k2T + (size_t)128 * 8192, out + c * Mc * H, mC);
  }
}